// Round 7
// baseline (379.690 us; speedup 1.0000x reference)
//
#include <hip/hip_runtime.h>
#include <stdint.h>

#define TOKENS 16384
#define D_IN   4096
#define D_OUT  4096
#define NKT    64   // K-tiles of 64 i8

typedef int v4i  __attribute__((ext_vector_type(4)));
typedef int v16i __attribute__((ext_vector_type(16)));

__device__ __forceinline__ void gl_lds16(const void* g, void* l) {
    __builtin_amdgcn_global_load_lds(
        (const __attribute__((address_space(1))) void*)g,
        (__attribute__((address_space(3))) void*)l, 16, 0, 0);
}

#define BARRIER() __builtin_amdgcn_s_barrier()

__device__ __forceinline__ unsigned sgnb(float f) {
    return (unsigned)(unsigned char)(signed char)((f > 0.f) - (f < 0.f));
}

// ---------------------------------------------------------------------------
// Packed image for 32x32x32 i8 MFMA fragments (UNCHANGED from R6, verified
// absmax=0, bank-conflict 0).
// A: [mb(128)][kt(64)][u(4)][ks(2)][1KB]   row = mb*128+u*32+r, k = kt*64+ks*32+..
// B: [nb(16)][kt(64)][u(8)][ks(2)][1KB]
// Each 1KB fragment is lane-linear (lane*16) for both ds_read_b128 and
// global_load_dwordx4.
// ---------------------------------------------------------------------------

__global__ __launch_bounds__(256) void pack_x_abssum(
        const float* __restrict__ x, signed char* __restrict__ xp,
        float* __restrict__ partials) {
    __shared__ unsigned char img[16384];   // two 8KB kt-units
    __shared__ float wsum[4];
    const int b   = blockIdx.x;            // 128*32 = 4096 blocks
    const int mb  = b >> 5;
    const int kt2 = b & 31;                // pair of kt units
    const int t   = threadIdx.x;
    const float* src = x + (size_t)mb * 128 * D_IN + kt2 * 128;
    float accum = 0.f;
#pragma unroll
    for (int p = 0; p < 16; ++p) {
        const int idx = p * 256 + t;       // 128 rows x 32 float4
        const int r   = idx >> 5;
        const int c4  = idx & 31;
        float4 v = *(const float4*)(src + (size_t)r * D_IN + c4 * 4);
        unsigned w = sgnb(v.x) | (sgnb(v.y) << 8) | (sgnb(v.z) << 16) | (sgnb(v.w) << 24);
        const int kl = (c4 * 4) & 63;      // k within the 64-k unit
        const int off = ((c4 >= 16) ? 8192 : 0)
                      + (r >> 5) * 2048 + (kl >> 5) * 1024 + ((kl >> 4) & 1) * 512
                      + (r & 31) * 16 + (kl & 15);
        *(unsigned*)&img[off] = w;
        accum += fabsf(v.x) + fabsf(v.y) + fabsf(v.z) + fabsf(v.w);
    }
    __syncthreads();
    unsigned* dst = (unsigned*)(xp + ((size_t)mb * 64 + kt2 * 2) * 8192);
    const unsigned* s32 = (const unsigned*)img;
#pragma unroll
    for (int p = 0; p < 16; ++p) dst[p * 256 + t] = s32[p * 256 + t];
#pragma unroll
    for (int o = 32; o > 0; o >>= 1) accum += __shfl_down(accum, o);
    if ((t & 63) == 0) wsum[t >> 6] = accum;
    __syncthreads();
    if (t == 0) partials[b] = wsum[0] + wsum[1] + wsum[2] + wsum[3];
}

__global__ void reduce_partials(const float* __restrict__ p, float* __restrict__ s) {
    __shared__ float ws[4];
    float a = 0.f;
    for (int i = threadIdx.x; i < 4096; i += 256) a += p[i];
#pragma unroll
    for (int o = 32; o > 0; o >>= 1) a += __shfl_down(a, o);
    if ((threadIdx.x & 63) == 0) ws[threadIdx.x >> 6] = a;
    __syncthreads();
    if (threadIdx.x == 0) s[0] = ws[0] + ws[1] + ws[2] + ws[3];
}

__global__ __launch_bounds__(256) void pack_w_kernel(
        const float* __restrict__ wsrc, signed char* __restrict__ wp) {
    __shared__ unsigned char img[16384];
    const int b  = blockIdx.x;             // 16*64 = 1024 blocks
    const int nb = b >> 6;
    const int kt = b & 63;
    const int t  = threadIdx.x;
    const float* src = wsrc + (size_t)nb * 256 * D_IN + kt * 64;
#pragma unroll
    for (int p = 0; p < 16; ++p) {
        const int idx = p * 256 + t;       // 256 rows x 16 float4
        const int r   = idx >> 4;
        const int c4  = idx & 15;
        float4 v = *(const float4*)(src + (size_t)r * D_IN + c4 * 4);
        unsigned w = sgnb(v.x) | (sgnb(v.y) << 8) | (sgnb(v.z) << 16) | (sgnb(v.w) << 24);
        const int kl = c4 * 4;
        const int off = (r >> 5) * 2048 + (kl >> 5) * 1024 + ((kl >> 4) & 1) * 512
                      + (r & 31) * 16 + (kl & 15);
        *(unsigned*)&img[off] = w;
    }
    __syncthreads();
    unsigned* dst = (unsigned*)(wp + ((size_t)nb * 64 + kt) * 16384);
    const unsigned* s32 = (const unsigned*)img;
#pragma unroll
    for (int p = 0; p < 16; ++p) dst[p * 256 + t] = s32[p * 256 + t];
}

// ---------------------------------------------------------------------------
// 128x256 tile, BK=64, 4 waves (2Mx2N), wave-tile 64x128, mfma_i32_32x32x32.
// AITER-pattern split pipeline:
//   B -> registers direct from L2 (8x global_load_dwordx4 /wave/tile, rotated
//        one tile ahead in bfE/bfO banks; compiler-managed vmcnt).
//   A -> LDS (dedupe; L3-sourced), triple-buffered, staged 2 tiles ahead via
//        gl_lds; manual counted vmcnt(10) before the per-tile barrier (the 10
//        in-flight = 8 B(t+1) + 2 A-stage(t+2): pipeline never drains).
// Uniform loop: tail staging wraps (&63) into dead buffers/regs (~3% extra
// fetch, zero branches).  2 blocks/CU (LDS 24KB, VGPR ~230).
// ---------------------------------------------------------------------------

#define STAGE_A(kt, buf) do {                                             \
    const signed char* g_ = aG + (size_t)((kt) & 63) * 8192;              \
    gl_lds16(g_ + t16,        (signed char*)&ldsA[buf][0] + t16);         \
    gl_lds16(g_ + 4096 + t16, (signed char*)&ldsA[buf][0] + 4096 + t16);  \
} while (0)

#define LOADB(dst, kt) do {                                               \
    const signed char* g_ = bG + (size_t)((kt) & 63) * 16384;             \
    dst[0] = *(const v4i*)(g_);          dst[1] = *(const v4i*)(g_ + 1024); \
    dst[2] = *(const v4i*)(g_ + 2048);   dst[3] = *(const v4i*)(g_ + 3072); \
    dst[4] = *(const v4i*)(g_ + 4096);   dst[5] = *(const v4i*)(g_ + 5120); \
    dst[6] = *(const v4i*)(g_ + 6144);   dst[7] = *(const v4i*)(g_ + 7168); \
} while (0)

#define MFMA32(d, a, b) __builtin_amdgcn_mfma_i32_32x32x32_i8((a), (b), (d), 0, 0, 0)

#define TILE_END_SYNC() do {                                              \
    asm volatile("s_waitcnt vmcnt(10)" ::: "memory");                     \
    __builtin_amdgcn_sched_barrier(0);                                    \
    asm volatile("s_waitcnt lgkmcnt(0)" ::: "memory");                    \
    __builtin_amdgcn_sched_barrier(0);                                    \
    BARRIER();                                                            \
} while (0)

// one K-tile: consume LDS buf `bc` + reg bank `bcur`; prefetch B(kt+1)->bnxt,
// stage A(kt+2)->buf bs.
#define DO_TILE(bc, bs, bcur, bnxt, kt) do {                              \
    const v4i* LA = &ldsA[bc][0];                                         \
    v4i a0 = LA[au * 128 + lane];                                         \
    v4i a1 = LA[au * 128 + 128 + lane];                                   \
    LOADB(bnxt, (kt) + 1);                                                \
    STAGE_A((kt) + 2, bs);                                                \
    _Pragma("unroll")                                                     \
    for (int an = 0; an < 4; ++an) {                                      \
        acc[0][an] = MFMA32(acc[0][an], a0, bcur[an * 2]);                \
        acc[1][an] = MFMA32(acc[1][an], a1, bcur[an * 2]);                \
    }                                                                     \
    a0 = LA[au * 128 + 64 + lane];                                        \
    a1 = LA[au * 128 + 192 + lane];                                       \
    _Pragma("unroll")                                                     \
    for (int an = 0; an < 4; ++an) {                                      \
        acc[0][an] = MFMA32(acc[0][an], a0, bcur[an * 2 + 1]);            \
        acc[1][an] = MFMA32(acc[1][an], a1, bcur[an * 2 + 1]);            \
    }                                                                     \
    TILE_END_SYNC();                                                      \
} while (0)

__global__ __launch_bounds__(256, 2) void bin_gemm(
    const signed char* __restrict__ Ap, const signed char* __restrict__ Bp,
    const float* __restrict__ bias, const float* __restrict__ sum_ptr,
    float* __restrict__ out) {
    __shared__ v4i ldsA[3][512];           // 3 x 8KB = 24KB

    const int t    = threadIdx.x;          // 0..255
    const int t16  = t * 16;
    const int lane = t & 63;
    const int wid  = t >> 6;               // 0..3
    const int wm   = wid >> 1;             // M half: rows wm*64
    const int wn   = wid & 1;              // N half: cols wn*128
    const int au   = wm * 2;               // A unit base (x2KB v4i-stride below)

    // XCD slice: xcd owns nb {2x,2x+1} -> 2MB packed B stays L2-resident.
    const int bid   = blockIdx.x;          // 2048 blocks
    const int xcd   = bid & 7;
    const int local = bid >> 3;            // 0..255
    const int nb    = xcd * 2 + (local & 1);
    const int mb    = local >> 1;          // 0..127

    const signed char* aG = Ap + (size_t)mb * 64 * 8192;
    const signed char* bG = Bp + (size_t)nb * 64 * 16384
                               + (size_t)(wn * 4) * 2048 + lane * 16;

    v16i acc[2][4];
#pragma unroll
    for (int i = 0; i < 2; ++i)
#pragma unroll
        for (int j = 0; j < 4; ++j) acc[i][j] = (v16i)(0);

    v4i bfE[8], bfO[8];

    // prologue: order matters for the counted wait:
    // [A0:2][B0:8][A1:2] -> vmcnt(10) waits A0 only (B0 compiler-tracked).
    STAGE_A(0, 0);
    LOADB(bfE, 0);
    STAGE_A(1, 1);
    asm volatile("s_waitcnt vmcnt(10)" ::: "memory");
    __builtin_amdgcn_sched_barrier(0);
    BARRIER();

    int c0 = 0, c1 = 1, c2 = 2;
    for (int it = 0; it < 32; ++it) {
        const int ktE = 2 * it;
        // even tile: LDS buf c0, regs bfE; prefetch bfO(ktE+1); stage A(ktE+2)->c2
        DO_TILE(c0, c2, bfE, bfO, ktE);
        // odd tile: LDS buf c1, regs bfO; prefetch bfE(ktE+2); stage A(ktE+3)->c0
        DO_TILE(c1, c0, bfO, bfE, ktE + 1);
        // rotate: tile 2it+2 reads buf (2it+2)%3 == old c2
        const int n0 = c2, n1 = c0, n2 = c1;
        c0 = n0; c1 = n1; c2 = n2;
    }

    // epilogue: out = (acc + bias) * scale
    // 32x32 C/D: col = lane&31, row = (g&3) + 8*(g>>2) + 4*(lane>>5)  [verified]
    const float scale = *sum_ptr * (1.0f / 67108864.0f);
    const int rbase = mb * 128 + wm * 64 + 4 * (lane >> 5);
    const int cbase = nb * 256 + wn * 128 + (lane & 31);
#pragma unroll
    for (int an = 0; an < 4; ++an) {
        const int col = cbase + an * 32;
        const float bb = bias[col];
#pragma unroll
        for (int am = 0; am < 2; ++am) {
            const int r0 = rbase + am * 32;
#pragma unroll
            for (int g = 0; g < 16; ++g) {
                const int row = r0 + (g & 3) + 8 * (g >> 2);
                out[(size_t)row * D_OUT + col] =
                    ((float)acc[am][an][g] + bb) * scale;
            }
        }
    }
}

extern "C" void kernel_launch(void* const* d_in, const int* in_sizes, int n_in,
                              void* d_out, int out_size, void* d_ws, size_t ws_size,
                              hipStream_t stream) {
    const float* x = (const float*)d_in[0];
    const float* W = (const float*)d_in[1];
    const float* b = (const float*)d_in[2];
    float* out = (float*)d_out;

    float* sum_ptr   = (float*)d_ws;                 // [0] result
    float* partials  = (float*)d_ws + 64;            // 4096 floats
    signed char* xs  = (signed char*)d_ws + 65536;
    signed char* wp  = xs + (size_t)TOKENS * D_IN;   // +64 MB

    pack_x_abssum<<<128 * 32, 256, 0, stream>>>(x, xs, partials);
    reduce_partials<<<1, 256, 0, stream>>>(partials, sum_ptr);
    pack_w_kernel<<<16 * 64, 256, 0, stream>>>(W, wp);
    bin_gemm<<<2048, 256, 0, stream>>>(xs, wp, b, sum_ptr, out);
}

// Round 8
// 349.925 us; speedup vs baseline: 1.0851x; 1.0851x over previous
//
#include <hip/hip_runtime.h>
#include <stdint.h>

#define TOKENS 16384
#define D_IN   4096
#define D_OUT  4096
#define NKT    64   // K-tiles of 64 i8

typedef int v4i  __attribute__((ext_vector_type(4)));
typedef int v16i __attribute__((ext_vector_type(16)));

__device__ __forceinline__ void gl_lds16(const void* g, void* l) {
    __builtin_amdgcn_global_load_lds(
        (const __attribute__((address_space(1))) void*)g,
        (__attribute__((address_space(3))) void*)l, 16, 0, 0);
}

#define BARRIER() __builtin_amdgcn_s_barrier()

__device__ __forceinline__ unsigned sgnb(float f) {
    return (unsigned)(unsigned char)(signed char)((f > 0.f) - (f < 0.f));
}

// ---------------------------------------------------------------------------
// Packed image for 32x32x32 i8 MFMA fragments (UNCHANGED since R6; verified
// absmax=0, SQ_LDS_BANK_CONFLICT=0).
// A: [mb(128)][kt(64)][u(4)][ks(2)][1KB]  row = mb*128+u*32+r, k = kt*64+ks*32+..
// B: [nb(16)][kt(64)][u(8)][ks(2)][1KB]
// Every 1KB fragment is lane-linear (lane*16) for gl_lds and ds_read_b128.
// ---------------------------------------------------------------------------

__global__ __launch_bounds__(256) void pack_x_abssum(
        const float* __restrict__ x, signed char* __restrict__ xp,
        float* __restrict__ partials) {
    __shared__ unsigned char img[16384];   // two 8KB kt-units
    __shared__ float wsum[4];
    const int b   = blockIdx.x;            // 128*32 = 4096 blocks
    const int mb  = b >> 5;
    const int kt2 = b & 31;
    const int t   = threadIdx.x;
    const float* src = x + (size_t)mb * 128 * D_IN + kt2 * 128;
    float accum = 0.f;
#pragma unroll
    for (int p = 0; p < 16; ++p) {
        const int idx = p * 256 + t;       // 128 rows x 32 float4
        const int r   = idx >> 5;
        const int c4  = idx & 31;
        float4 v = *(const float4*)(src + (size_t)r * D_IN + c4 * 4);
        unsigned w = sgnb(v.x) | (sgnb(v.y) << 8) | (sgnb(v.z) << 16) | (sgnb(v.w) << 24);
        const int kl = (c4 * 4) & 63;
        const int off = ((c4 >= 16) ? 8192 : 0)
                      + (r >> 5) * 2048 + (kl >> 5) * 1024 + ((kl >> 4) & 1) * 512
                      + (r & 31) * 16 + (kl & 15);
        *(unsigned*)&img[off] = w;
        accum += fabsf(v.x) + fabsf(v.y) + fabsf(v.z) + fabsf(v.w);
    }
    __syncthreads();
    unsigned* dst = (unsigned*)(xp + ((size_t)mb * 64 + kt2 * 2) * 8192);
    const unsigned* s32 = (const unsigned*)img;
#pragma unroll
    for (int p = 0; p < 16; ++p) dst[p * 256 + t] = s32[p * 256 + t];
#pragma unroll
    for (int o = 32; o > 0; o >>= 1) accum += __shfl_down(accum, o);
    if ((t & 63) == 0) wsum[t >> 6] = accum;
    __syncthreads();
    if (t == 0) partials[b] = wsum[0] + wsum[1] + wsum[2] + wsum[3];
}

__global__ void reduce_partials(const float* __restrict__ p, float* __restrict__ s) {
    __shared__ float ws[4];
    float a = 0.f;
    for (int i = threadIdx.x; i < 4096; i += 256) a += p[i];
#pragma unroll
    for (int o = 32; o > 0; o >>= 1) a += __shfl_down(a, o);
    if ((threadIdx.x & 63) == 0) ws[threadIdx.x >> 6] = a;
    __syncthreads();
    if (threadIdx.x == 0) s[0] = ws[0] + ws[1] + ws[2] + ws[3];
}

__global__ __launch_bounds__(256) void pack_w_kernel(
        const float* __restrict__ wsrc, signed char* __restrict__ wp) {
    __shared__ unsigned char img[16384];
    const int b  = blockIdx.x;             // 16*64 = 1024 blocks
    const int nb = b >> 6;
    const int kt = b & 63;
    const int t  = threadIdx.x;
    const float* src = wsrc + (size_t)nb * 256 * D_IN + kt * 64;
#pragma unroll
    for (int p = 0; p < 16; ++p) {
        const int idx = p * 256 + t;       // 256 rows x 16 float4
        const int r   = idx >> 4;
        const int c4  = idx & 15;
        float4 v = *(const float4*)(src + (size_t)r * D_IN + c4 * 4);
        unsigned w = sgnb(v.x) | (sgnb(v.y) << 8) | (sgnb(v.z) << 16) | (sgnb(v.w) << 24);
        const int kl = c4 * 4;
        const int off = (r >> 5) * 2048 + (kl >> 5) * 1024 + ((kl >> 4) & 1) * 512
                      + (r & 31) * 16 + (kl & 15);
        *(unsigned*)&img[off] = w;
    }
    __syncthreads();
    unsigned* dst = (unsigned*)(wp + ((size_t)nb * 64 + kt) * 16384);
    const unsigned* s32 = (const unsigned*)img;
#pragma unroll
    for (int p = 0; p < 16; ++p) dst[p * 256 + t] = s32[p * 256 + t];
}

// ---------------------------------------------------------------------------
// 128x256 tile, BK=64, 4 waves (2Mx2N), wave-tile 64x128, mfma_i32_32x32x32.
// CROSS-BARRIER REGISTER ROTATION (the R6 structure with the serial
// ds_read->MFMA chain removed):
//   iter t:  MFMA ks0(t)  [P regs, read >=1 cluster earlier]
//            stage(t+2) -> buf (t+2)%3
//            lgkmcnt(0); vmcnt(6|0); s_barrier       (ONE sync point)
//            read P <- ks0(t+1)                      (consumed next iter s1)
//            MFMA ks1(t)  [Q regs, read a full tile earlier]
//            read Q <- ks1(t+1)                      (consumed next iter s5)
// Race-safety: reads of buf(t+1) are post-barrier (all waves' vmcnt passed);
// lgkmcnt(0) before each barrier drains this wave's reads of buf(t+1) issued
// last iteration, so the stage that overwrites that buffer (>=1 barrier
// later) cannot collide. No MFMA depends on a same-iteration ds_read.
// 2 blocks/CU (LDS 72KB, launch_bounds(256,2) caps unified regs at 256).
// ---------------------------------------------------------------------------

#define STAGE(d, kt) do {                                               \
    signed char* L_ = (signed char*)&ldsA[d][0];                        \
    const signed char* ga_ = aG + (size_t)(kt) * 8192;                  \
    const signed char* gb_ = bG + (size_t)(kt) * 16384;                 \
    gl_lds16(ga_ + t16,         L_ + t16);                              \
    gl_lds16(ga_ + 4096 + t16,  L_ + 4096 + t16);                      \
    gl_lds16(gb_ + t16,         L_ + 8192 + t16);                      \
    gl_lds16(gb_ + 4096 + t16,  L_ + 12288 + t16);                     \
    gl_lds16(gb_ + 8192 + t16,  L_ + 16384 + t16);                     \
    gl_lds16(gb_ + 12288 + t16, L_ + 20480 + t16);                     \
} while (0)

#define READ_KS0(dst, bufv) do {                                        \
    const v4i* L_ = &ldsA[bufv][0];                                     \
    dst[0] = L_[auo + lane];            dst[1] = L_[auo + 128 + lane];  \
    dst[2] = L_[buo + lane];            dst[3] = L_[buo + 128 + lane];  \
    dst[4] = L_[buo + 256 + lane];      dst[5] = L_[buo + 384 + lane];  \
} while (0)

#define READ_KS1(dst, bufv) do {                                        \
    const v4i* L_ = &ldsA[bufv][0];                                     \
    dst[0] = L_[auo + 64 + lane];       dst[1] = L_[auo + 192 + lane];  \
    dst[2] = L_[buo + 64 + lane];       dst[3] = L_[buo + 192 + lane];  \
    dst[4] = L_[buo + 320 + lane];      dst[5] = L_[buo + 448 + lane];  \
} while (0)

#define MFMA32(d, a, b) __builtin_amdgcn_mfma_i32_32x32x32_i8((a), (b), (d), 0, 0, 0)

#define CLUSTER(F) do {                                                 \
    _Pragma("unroll")                                                   \
    for (int an = 0; an < 4; ++an) {                                    \
        acc[0][an] = MFMA32(acc[0][an], F[0], F[2 + an]);               \
        acc[1][an] = MFMA32(acc[1][an], F[1], F[2 + an]);               \
    }                                                                   \
} while (0)

__global__ __launch_bounds__(256, 2) void bin_gemm(
    const signed char* __restrict__ Ap, const signed char* __restrict__ Bp,
    const float* __restrict__ bias, const float* __restrict__ sum_ptr,
    float* __restrict__ out) {
    __shared__ v4i ldsA[3][1536];          // 3 x 24KB = 72KB

    const int t    = threadIdx.x;          // 0..255
    const int t16  = t * 16;
    const int lane = t & 63;
    const int wid  = t >> 6;               // 0..3
    const int wm   = wid >> 1;             // M half: rows wm*64
    const int wn   = wid & 1;              // N half: cols wn*128
    const int auo  = (wm * 2) * 128;       // A v4i-offset base
    const int buo  = 512 + (wn * 4) * 128; // B v4i-offset base

    // XCD slice: xcd owns nb {2x,2x+1} (2MB packed B L2-resident).
    const int bid   = blockIdx.x;          // 2048 blocks
    const int xcd   = bid & 7;
    const int local = bid >> 3;            // 0..255
    const int nb    = xcd * 2 + (local & 1);
    const int mb    = local >> 1;          // 0..127

    const signed char* aG = Ap + (size_t)mb * 64 * 8192;
    const signed char* bG = Bp + (size_t)nb * 64 * 16384;

    v16i acc[2][4];
#pragma unroll
    for (int i = 0; i < 2; ++i)
#pragma unroll
        for (int j = 0; j < 4; ++j) acc[i][j] = (v16i)(0);

    v4i P[6], Q[6];                        // ks0 / ks1 fragment banks

    // prologue: stage kt0,kt1; wait kt0; first fragment loads
    STAGE(0, 0);
    STAGE(1, 1);
    asm volatile("s_waitcnt vmcnt(6)" ::: "memory");
    BARRIER();
    READ_KS0(P, 0);
    READ_KS1(Q, 0);

    int cb = 0, rb = 1, sb = 2;            // cur / read(t+1) / stage(t+2) bufs
    for (int kt = 0; kt < NKT - 1; ++kt) {
        // s1: ks0(t) — inputs >=1 cluster old
        CLUSTER(P);
        // s2: stage(t+2)
        if (kt < NKT - 2) STAGE(sb, kt + 2);
        // s3: single sync point
        asm volatile("s_waitcnt lgkmcnt(0)" ::: "memory");
        if (kt == NKT - 2) { asm volatile("s_waitcnt vmcnt(0)" ::: "memory"); }
        else               { asm volatile("s_waitcnt vmcnt(6)" ::: "memory"); }
        BARRIER();
        // s4a: next tile's ks0 fragments (consumed next iteration s1)
        READ_KS0(P, rb);
        // s5: ks1(t) — Q read a full tile ago
        CLUSTER(Q);
        // s4b: next tile's ks1 fragments (consumed next iteration s5)
        READ_KS1(Q, rb);
        // rotate buffers
        const int n0 = rb, n1 = sb, n2 = cb;
        cb = n0; rb = n1; sb = n2;
    }
    // final tile (fragments already in P,Q)
    CLUSTER(P);
    CLUSTER(Q);

    // epilogue: out = (acc + bias) * scale
    // 32x32 C/D: col = lane&31, row = (g&3) + 8*(g>>2) + 4*(lane>>5)  [verified]
    const float scale = *sum_ptr * (1.0f / 67108864.0f);
    const int rbase = mb * 128 + wm * 64 + 4 * (lane >> 5);
    const int cbase = nb * 256 + wn * 128 + (lane & 31);
#pragma unroll
    for (int an = 0; an < 4; ++an) {
        const int col = cbase + an * 32;
        const float bb = bias[col];
#pragma unroll
        for (int am = 0; am < 2; ++am) {
            const int r0 = rbase + am * 32;
#pragma unroll
            for (int g = 0; g < 16; ++g) {
                const int row = r0 + (g & 3) + 8 * (g >> 2);
                out[(size_t)row * D_OUT + col] =
                    ((float)acc[am][an][g] + bb) * scale;
            }
        }
    }
}

extern "C" void kernel_launch(void* const* d_in, const int* in_sizes, int n_in,
                              void* d_out, int out_size, void* d_ws, size_t ws_size,
                              hipStream_t stream) {
    const float* x = (const float*)d_in[0];
    const float* W = (const float*)d_in[1];
    const float* b = (const float*)d_in[2];
    float* out = (float*)d_out;

    float* sum_ptr   = (float*)d_ws;                 // [0] result
    float* partials  = (float*)d_ws + 64;            // 4096 floats
    signed char* xs  = (signed char*)d_ws + 65536;
    signed char* wp  = xs + (size_t)TOKENS * D_IN;   // +64 MB

    pack_x_abssum<<<128 * 32, 256, 0, stream>>>(x, xs, partials);
    reduce_partials<<<1, 256, 0, stream>>>(partials, sum_ptr);
    pack_w_kernel<<<16 * 64, 256, 0, stream>>>(W, wp);
    bin_gemm<<<2048, 256, 0, stream>>>(xs, wp, b, sum_ptr, out);
}